// Round 5
// baseline (493.794 us; speedup 1.0000x reference)
//
#include <hip/hip_runtime.h>

typedef short v8s __attribute__((ext_vector_type(8)));
typedef float v4f __attribute__((ext_vector_type(4)));
typedef unsigned short v4us __attribute__((ext_vector_type(4)));

__device__ __forceinline__ unsigned short f2bf(float x) {
  union { float f; unsigned int u; } c; c.f = x;
  unsigned int u = c.u;
  return (unsigned short)((u + 0x7fffu + ((u >> 16) & 1u)) >> 16);
}
__device__ __forceinline__ float bf2f(unsigned int hi16) {
  union { unsigned int u; float f; } c; c.u = hi16 << 16;
  return c.f;
}
__device__ __forceinline__ ushort2 pk(float2 v) {
  ushort2 p; p.x = f2bf(v.x); p.y = f2bf(v.y); return p;
}

// Fold BN scale/shift AND the lin_l bias:  out = relu(z*s + t'), t' = (b - rm)*s + be.
// Also zeroes the gather sentinel row N of bufA.
__global__ void bn_fold_k(const float* __restrict__ g1, const float* __restrict__ be1,
                          const float* __restrict__ rm1, const float* __restrict__ rv1,
                          const float* __restrict__ b1,
                          const float* __restrict__ g2, const float* __restrict__ be2,
                          const float* __restrict__ rm2, const float* __restrict__ rv2,
                          const float* __restrict__ b2,
                          float* __restrict__ s1, float* __restrict__ t1,
                          float* __restrict__ s2, float* __restrict__ t2,
                          unsigned short* __restrict__ bufA, int N) {
  int i = threadIdx.x;
  if (i < 128) {
    float sv = g1[i] * rsqrtf(rv1[i] + 1e-5f);
    s1[i] = sv; t1[i] = (b1[i] - rm1[i]) * sv + be1[i];
    float sw = g2[i] * rsqrtf(rv2[i] + 1e-5f);
    s2[i] = sw; t2[i] = (b2[i] - rm2[i]) * sw + be2[i];
  }
  if (i < 64) ((unsigned int*)(bufA + (long)N * 128))[i] = 0u;
}

// B pack for 256-wide GEMM: wpk[kc*8192 + n*32 + kk]; cols 0:128 = Wl, 128:256 = Wr.
// k >= K rows are ZERO (relied upon by the K-pad MFMA slots).
template<int K, int KC>
__global__ void pack2_k(const float* __restrict__ Wl, const float* __restrict__ Wr,
                        unsigned short* __restrict__ wpk) {
  int i = blockIdx.x * 256 + threadIdx.x;
  if (i >= KC * 8192) return;
  int kk = i & 31, n = (i >> 5) & 255, kc = i >> 13;
  int k = kc * 32 + kk;
  float v = 0.f;
  if (k < K) v = (n < 128) ? Wl[k * 128 + n] : Wr[k * 128 + (n - 128)];
  wpk[i] = f2bf(v);
}

// ---------- CSR build ----------
__global__ void zero_i_k(int* __restrict__ p, int n) {
  int i = blockIdx.x * 256 + threadIdx.x;
  if (i < n) p[i] = 0;
}
__global__ void count_k(const int* __restrict__ dst, int* __restrict__ degi, int E) {
  int i = blockIdx.x * 256 + threadIdx.x;
  if (i < E) atomicAdd(&degi[dst[i]], 1);
}
__global__ __launch_bounds__(256) void scan1_k(const int* __restrict__ degi,
                                               int* __restrict__ rowptr,
                                               int* __restrict__ bsum, int N) {
  __shared__ int sd[256];
  const int t = threadIdx.x;
  const int base = blockIdx.x * 1024 + t * 4;
  int v[4];
#pragma unroll
  for (int j = 0; j < 4; ++j) v[j] = (base + j < N) ? degi[base + j] : 0;
  const int tot = v[0] + v[1] + v[2] + v[3];
  sd[t] = tot;
  __syncthreads();
  for (int off = 1; off < 256; off <<= 1) {
    int o = (t >= off) ? sd[t - off] : 0;
    __syncthreads();
    sd[t] += o;
    __syncthreads();
  }
  int e = sd[t] - tot;
#pragma unroll
  for (int j = 0; j < 4; ++j) {
    if (base + j < N) rowptr[base + j] = e;
    e += v[j];
  }
  if (t == 255) bsum[blockIdx.x] = sd[255];
}
__global__ __launch_bounds__(256) void scan2_k(int* __restrict__ bsum, int nb) {
  __shared__ int sd[256];
  const int t = threadIdx.x;
  const int v = (t < nb) ? bsum[t] : 0;
  sd[t] = v;
  __syncthreads();
  for (int off = 1; off < 256; off <<= 1) {
    int o = (t >= off) ? sd[t - off] : 0;
    __syncthreads();
    sd[t] += o;
    __syncthreads();
  }
  if (t < nb) bsum[t] = sd[t] - v;
}
__global__ void scan3_k(int* __restrict__ rowptr, int* __restrict__ cursor,
                        const int* __restrict__ bsum, int N, int E) {
  int i = blockIdx.x * 256 + threadIdx.x;
  if (i < N) {
    int v = rowptr[i] + bsum[i >> 10];
    rowptr[i] = v;
    cursor[i] = v;
  } else if (i == N) {
    rowptr[N] = E;
  }
}
__global__ void fill_k(const int* __restrict__ src, const int* __restrict__ dst,
                       int* __restrict__ cursor, int* __restrict__ nbr, int E) {
  int i = blockIdx.x * 256 + threadIdx.x;
  if (i < E) {
    int p = atomicAdd(&cursor[dst[i]], 1);
    nbr[p] = src[i];
  }
}

// ---------- dense GEMM, LDS-FREE: A(64 rows) x [Wl|Wr](256 cols) -> Ol, Or ----------
// Per wave: 32 nodes ((wave&1)*32 sub-tile, acc mt=0,1) x 128 features ((wave>>1)*128,
// acc nt=0..7). Node fragments (MFMA B-operand: col=l16 -> node, k=quad*8+j) load
// DIRECTLY from the row-major source: a wave covers 16 rows x 128 contiguous bytes.
// Weight fragments (A-operand: row=l16 -> feature) stream from L2-resident wpk; each
// wf feeds both mt MFMAs. No LDS, no staging barrier; global loads pipeline against
// MFMA across the whole k-loop.
// SRCF32: fp32 stride-130 source, convert in-register. kc==4 handles k=128..159:
//   only k=128,129 carry data; wpk rows k>=130 are zero so junk/zero nf there is inert.
// In-place (L2): Or aliases Asrc. Waves 0,1 read rows (w&1)*32..+32 and write Ol;
// waves 2,3 read the same rows and write Or -> one __syncthreads() between the
// k-loop (all reads consumed by MFMA) and the epilogue stores makes it race-free.
template<int KC, bool SRCF32>
__global__ __launch_bounds__(256) void gemm2_k(const void* __restrict__ Asrc,
                                               const unsigned short* __restrict__ wpk,
                                               unsigned short* __restrict__ Ol,
                                               unsigned short* __restrict__ Or, int N) {
  const int tid = threadIdx.x;
  const int wave = tid >> 6, lane = tid & 63;
  const int quad = lane >> 4, l16 = lane & 15;
  const int node0 = blockIdx.x * 64;
  const int r0 = node0 + (wave & 1) * 32 + l16;   // + mt*16
  unsigned short* ob = (wave < 2) ? Ol : Or;
  const int fb = (wave >> 1) * 128;               // feature base in wpk

  v4f acc[2][8];
#pragma unroll
  for (int mt = 0; mt < 2; ++mt)
#pragma unroll
    for (int nt = 0; nt < 8; ++nt) acc[mt][nt] = (v4f){0.f, 0.f, 0.f, 0.f};

#pragma unroll
  for (int kc = 0; kc < KC; ++kc) {
    v8s nf[2];
    if constexpr (SRCF32) {
      if (kc < 4) {
#pragma unroll
        for (int mt = 0; mt < 2; ++mt) {
          const int row = r0 + mt * 16;
          float4 a = {0.f, 0.f, 0.f, 0.f}, b = {0.f, 0.f, 0.f, 0.f};
          if (row < N) {
            const float* xr = (const float*)Asrc + (long)row * 130 + kc * 32 + quad * 8;
            a = *(const float4*)(xr);
            b = *(const float4*)(xr + 4);
          }
          v8s t;
          t[0] = (short)f2bf(a.x); t[1] = (short)f2bf(a.y);
          t[2] = (short)f2bf(a.z); t[3] = (short)f2bf(a.w);
          t[4] = (short)f2bf(b.x); t[5] = (short)f2bf(b.y);
          t[6] = (short)f2bf(b.z); t[7] = (short)f2bf(b.w);
          nf[mt] = t;
        }
      } else {
        // k = 128 + quad*8 + j; only quad 0, j=0,1 (k=128,129) carry data.
#pragma unroll
        for (int mt = 0; mt < 2; ++mt) {
          const int row = r0 + mt * 16;
          float2 a = make_float2(0.f, 0.f);
          if (quad == 0 && row < N)
            a = *(const float2*)((const float*)Asrc + (long)row * 130 + 128);
          v8s t = {0, 0, 0, 0, 0, 0, 0, 0};
          t[0] = (short)f2bf(a.x); t[1] = (short)f2bf(a.y);
          nf[mt] = t;
        }
      }
    } else {
#pragma unroll
      for (int mt = 0; mt < 2; ++mt) {
        const int row = r0 + mt * 16;
        v8s t = {0, 0, 0, 0, 0, 0, 0, 0};
        if (row < N)
          t = *(const v8s*)((const unsigned short*)Asrc + (long)row * 128 + kc * 32 + quad * 8);
        nf[mt] = t;
      }
    }
    const unsigned short* wk = wpk + kc * 8192 + (fb + l16) * 32 + quad * 8;
#pragma unroll
    for (int nt = 0; nt < 8; ++nt) {
      v8s wf = *(const v8s*)(wk + nt * 512);
      acc[0][nt] = __builtin_amdgcn_mfma_f32_16x16x32_bf16(wf, nf[0], acc[0][nt], 0, 0, 0);
      acc[1][nt] = __builtin_amdgcn_mfma_f32_16x16x32_bf16(wf, nf[1], acc[1][nt], 0, 0, 0);
    }
  }

  __syncthreads();   // in-place safety: all of this block's row reads precede any write

  // D layout: col = l16 -> node, row = quad*4+r -> feature offset within nt*16.
  // Each lane: 8 stores of 4 consecutive bf16 feats (8 B), 16 rows x 32 B per wave instr.
#pragma unroll
  for (int mt = 0; mt < 2; ++mt) {
    const int row = r0 + mt * 16;
    if (row < N) {
#pragma unroll
      for (int nt = 0; nt < 8; ++nt) {
        v4us v;
        v[0] = f2bf(acc[mt][nt][0]);
        v[1] = f2bf(acc[mt][nt][1]);
        v[2] = f2bf(acc[mt][nt][2]);
        v[3] = f2bf(acc[mt][nt][3]);
        *(v4us*)(ob + (long)row * 128 + nt * 16 + quad * 4) = v;
      }
    }
  }
}

// ---------- fused aggregate: out = relu((mean(gsrc[nbr]) + rsrc[node]) * s + t) ----------
// 4 nodes/wave, 16 nodes/block. 256-B rows: lane reads one u32 (2 bf16) per neighbor row.
// In-place allowed: out may alias rsrc (root read data-depends before the write).
template<bool OUTF32>
__global__ __launch_bounds__(256) void spmm_f_k(const unsigned short* __restrict__ gsrc,
                                                const unsigned short* __restrict__ rsrc,
                                                const int* __restrict__ rowptr,
                                                const int* __restrict__ nbr,
                                                const float* __restrict__ sc,
                                                const float* __restrict__ tc,
                                                void* __restrict__ out, int N) {
  const int w = threadIdx.x >> 6, lane = threadIdx.x & 63;
  const int nb = blockIdx.x * 16 + w * 4;
  if (nb >= N) return;

  int rp = 0;
  if (lane <= 4 && nb + lane <= N) rp = rowptr[nb + lane];
  int d[4], r0[4], myn[4];
  float2 a[4];
#pragma unroll
  for (int r = 0; r < 4; ++r) {
    r0[r] = __shfl(rp, r, 64);
    const int r1 = __shfl(rp, r + 1, 64);
    d[r] = (nb + r < N) ? (r1 - r0[r]) : 0;
    a[r] = make_float2(0.f, 0.f);
    myn[r] = N;
    if (lane < min(d[r], 64)) myn[r] = nbr[r0[r] + lane];
  }
  const int dm = max(max(d[0], d[1]), max(d[2], d[3]));

  if (dm <= 64) {
    for (int e0 = 0; e0 < dm; e0 += 8) {
      unsigned int u[4][8];
#pragma unroll
      for (int j = 0; j < 8; ++j)
#pragma unroll
        for (int r = 0; r < 4; ++r) {
          const int e = e0 + j;
          const int idx = (e < d[r]) ? __shfl(myn[r], e, 64) : N;
          u[r][j] = *(const unsigned int*)(gsrc + (long)idx * 128 + 2 * lane);
        }
#pragma unroll
      for (int r = 0; r < 4; ++r)
#pragma unroll
        for (int j = 0; j < 8; ++j) {
          a[r].x += bf2f(u[r][j] & 0xffffu);
          a[r].y += bf2f(u[r][j] >> 16);
        }
    }
  } else {  // rare huge-degree fallback
    for (int r = 0; r < 4; ++r) {
      for (int base = r0[r]; base < r0[r] + d[r]; base += 64) {
        const int cnt = min(64, r0[r] + d[r] - base);
        const int mn = (lane < cnt) ? nbr[base + lane] : N;
        for (int e = 0; e < cnt; ++e) {
          const unsigned int uu =
              *(const unsigned int*)(gsrc + (long)__shfl(mn, e, 64) * 128 + 2 * lane);
          a[r].x += bf2f(uu & 0xffffu);
          a[r].y += bf2f(uu >> 16);
        }
      }
    }
  }

  const float2 sv = *(const float2*)(sc + 2 * lane);
  const float2 tv = *(const float2*)(tc + 2 * lane);
#pragma unroll
  for (int r = 0; r < 4; ++r) {
    if (nb + r < N) {
      const float inv = 1.0f / fmaxf((float)d[r], 1.0f);
      const unsigned int ur = *(const unsigned int*)(rsrc + (long)(nb + r) * 128 + 2 * lane);
      float yx = a[r].x * inv + bf2f(ur & 0xffffu);
      float yy = a[r].y * inv + bf2f(ur >> 16);
      yx = fmaxf(yx * sv.x + tv.x, 0.f);
      yy = fmaxf(yy * sv.y + tv.y, 0.f);
      if (OUTF32) {
        *(float2*)((float*)out + (long)(nb + r) * 128 + 2 * lane) = make_float2(yx, yy);
      } else {
        *(ushort2*)((unsigned short*)out + (long)(nb + r) * 128 + 2 * lane) =
            pk(make_float2(yx, yy));
      }
    }
  }
}

extern "C" void kernel_launch(void* const* d_in, const int* in_sizes, int n_in,
                              void* d_out, int out_size, void* d_ws, size_t ws_size,
                              hipStream_t stream) {
  const float* x   = (const float*)d_in[0];
  const int*   ei  = (const int*)d_in[1];
  const float* W1l = (const float*)d_in[2];
  const float* b1  = (const float*)d_in[3];
  const float* W1r = (const float*)d_in[4];
  const float* g1  = (const float*)d_in[5];
  const float* be1 = (const float*)d_in[6];
  const float* rm1 = (const float*)d_in[7];
  const float* rv1 = (const float*)d_in[8];
  const float* W2l = (const float*)d_in[9];
  const float* b2  = (const float*)d_in[10];
  const float* W2r = (const float*)d_in[11];
  const float* g2  = (const float*)d_in[12];
  const float* be2 = (const float*)d_in[13];
  const float* rm2 = (const float*)d_in[14];
  const float* rv2 = (const float*)d_in[15];

  const int E = in_sizes[1] / 2;
  const int N = in_sizes[0] / 130;
  const int* src = ei;
  const int* dst = ei + E;

  // workspace carve: two (N+1)x128 bf16 ping-pong buffers + packs + CSR (~106 MB)
  unsigned short* bufA = (unsigned short*)d_ws;            // P1l -> P2l (gather targets)
  unsigned short* bufB = bufA + (size_t)(N + 1) * 128;     // P1r -> h1 -> P2r (root/in-place)
  unsigned short* wpka = bufB + (size_t)(N + 1) * 128;     // 5*8192
  unsigned short* wpkb = wpka + 5 * 8192;                  // 4*8192
  float* s1 = (float*)(wpkb + 4 * 8192);
  float* t1 = s1 + 128;
  float* s2 = t1 + 128;
  float* t2 = s2 + 128;
  int* degi   = (int*)(t2 + 128);   // N (reused as cursor)
  int* rowptr = degi + N;           // N+1
  int* bsum   = rowptr + N + 1;     // 256
  int* nbr    = bsum + 256;         // E

  hipLaunchKernelGGL(bn_fold_k, dim3(1), dim3(128), 0, stream,
                     g1, be1, rm1, rv1, b1, g2, be2, rm2, rv2, b2,
                     s1, t1, s2, t2, bufA, N);
  hipLaunchKernelGGL((pack2_k<130, 5>), dim3(160), dim3(256), 0, stream, W1l, W1r, wpka);
  hipLaunchKernelGGL((pack2_k<128, 4>), dim3(128), dim3(256), 0, stream, W2l, W2r, wpkb);

  // CSR build
  hipLaunchKernelGGL(zero_i_k, dim3((N + 255) / 256), dim3(256), 0, stream, degi, N);
  hipLaunchKernelGGL(count_k, dim3((E + 255) / 256), dim3(256), 0, stream, dst, degi, E);
  const int nb = (N + 1023) / 1024;
  hipLaunchKernelGGL(scan1_k, dim3(nb), dim3(256), 0, stream, degi, rowptr, bsum, N);
  hipLaunchKernelGGL(scan2_k, dim3(1), dim3(256), 0, stream, bsum, nb);
  hipLaunchKernelGGL(scan3_k, dim3((N + 256) / 256), dim3(256), 0, stream,
                     rowptr, degi, bsum, N, E);
  hipLaunchKernelGGL(fill_k, dim3((E + 255) / 256), dim3(256), 0, stream,
                     src, dst, degi, nbr, E);

  const int ngb = (N + 63) / 64;
  const int nsb = (N + 15) / 16;

  // layer 1: P1l|P1r = x @ [W1l|W1r]; h1 = relu((mean(P1l[nbr]) + P1r)*s1 + t1') over P1r
  hipLaunchKernelGGL((gemm2_k<5, true>), dim3(ngb), dim3(256), 0, stream,
                     (const void*)x, wpka, bufA, bufB, N);
  hipLaunchKernelGGL((spmm_f_k<false>), dim3(nsb), dim3(256), 0, stream,
                     bufA, bufB, rowptr, nbr, s1, t1, (void*)bufB, N);
  // layer 2: P2l|P2r = h1 @ [W2l|W2r] (in-place over bufA/bufB); out fp32
  hipLaunchKernelGGL((gemm2_k<4, false>), dim3(ngb), dim3(256), 0, stream,
                     (const void*)bufB, wpkb, bufA, bufB, N);
  hipLaunchKernelGGL((spmm_f_k<true>), dim3(nsb), dim3(256), 0, stream,
                     bufA, bufB, rowptr, nbr, s2, t2, d_out, N);
}

// Round 6
// 460.826 us; speedup vs baseline: 1.0715x; 1.0715x over previous
//
#include <hip/hip_runtime.h>

typedef short v8s __attribute__((ext_vector_type(8)));
typedef float v4f __attribute__((ext_vector_type(4)));
typedef unsigned short v4us __attribute__((ext_vector_type(4)));

__device__ __forceinline__ unsigned short f2bf(float x) {
  union { float f; unsigned int u; } c; c.f = x;
  unsigned int u = c.u;
  return (unsigned short)((u + 0x7fffu + ((u >> 16) & 1u)) >> 16);
}
__device__ __forceinline__ float bf2f(unsigned int hi16) {
  union { unsigned int u; float f; } c; c.u = hi16 << 16;
  return c.f;
}
__device__ __forceinline__ ushort2 pk(float2 v) {
  ushort2 p; p.x = f2bf(v.x); p.y = f2bf(v.y); return p;
}

// Fold BN scale/shift AND the lin_l bias:  out = relu(z*s + t'), t' = (b - rm)*s + be.
// Also zeroes the gather sentinel row N of bufA (rows < N only are ever written later).
__global__ void bn_fold_k(const float* __restrict__ g1, const float* __restrict__ be1,
                          const float* __restrict__ rm1, const float* __restrict__ rv1,
                          const float* __restrict__ b1,
                          const float* __restrict__ g2, const float* __restrict__ be2,
                          const float* __restrict__ rm2, const float* __restrict__ rv2,
                          const float* __restrict__ b2,
                          float* __restrict__ s1, float* __restrict__ t1,
                          float* __restrict__ s2, float* __restrict__ t2,
                          unsigned short* __restrict__ bufA, int N) {
  int i = threadIdx.x;
  if (i < 128) {
    float sv = g1[i] * rsqrtf(rv1[i] + 1e-5f);
    s1[i] = sv; t1[i] = (b1[i] - rm1[i]) * sv + be1[i];
    float sw = g2[i] * rsqrtf(rv2[i] + 1e-5f);
    s2[i] = sw; t2[i] = (b2[i] - rm2[i]) * sw + be2[i];
  }
  if (i < 64) ((unsigned int*)(bufA + (long)N * 128))[i] = 0u;
}

// Pack one 128-col weight into MFMA A-operand fragments:
// wpk[kc*4096 + n*32 + kk], n in [0,128). k >= K rows are ZERO (K-pad relies on this).
template<int K, int KC>
__global__ void pack1_k(const float* __restrict__ W, unsigned short* __restrict__ wpk) {
  int i = blockIdx.x * 256 + threadIdx.x;
  if (i >= KC * 4096) return;
  int kk = i & 31, n = (i >> 5) & 127, kc = i >> 12;
  int k = kc * 32 + kk;
  wpk[i] = (k < K) ? f2bf(W[k * 128 + n]) : (unsigned short)0;
}

// ---------- CSR build ----------
__global__ void zero_i_k(int* __restrict__ p, int n) {
  int i = blockIdx.x * 256 + threadIdx.x;
  if (i < n) p[i] = 0;
}
__global__ void count_k(const int* __restrict__ dst, int* __restrict__ degi, int E) {
  int i = blockIdx.x * 256 + threadIdx.x;
  if (i < E) atomicAdd(&degi[dst[i]], 1);
}
__global__ __launch_bounds__(256) void scan1_k(const int* __restrict__ degi,
                                               int* __restrict__ rowptr,
                                               int* __restrict__ bsum, int N) {
  __shared__ int sd[256];
  const int t = threadIdx.x;
  const int base = blockIdx.x * 1024 + t * 4;
  int v[4];
#pragma unroll
  for (int j = 0; j < 4; ++j) v[j] = (base + j < N) ? degi[base + j] : 0;
  const int tot = v[0] + v[1] + v[2] + v[3];
  sd[t] = tot;
  __syncthreads();
  for (int off = 1; off < 256; off <<= 1) {
    int o = (t >= off) ? sd[t - off] : 0;
    __syncthreads();
    sd[t] += o;
    __syncthreads();
  }
  int e = sd[t] - tot;
#pragma unroll
  for (int j = 0; j < 4; ++j) {
    if (base + j < N) rowptr[base + j] = e;
    e += v[j];
  }
  if (t == 255) bsum[blockIdx.x] = sd[255];
}
__global__ __launch_bounds__(256) void scan2_k(int* __restrict__ bsum, int nb) {
  __shared__ int sd[256];
  const int t = threadIdx.x;
  const int v = (t < nb) ? bsum[t] : 0;
  sd[t] = v;
  __syncthreads();
  for (int off = 1; off < 256; off <<= 1) {
    int o = (t >= off) ? sd[t - off] : 0;
    __syncthreads();
    sd[t] += o;
    __syncthreads();
  }
  if (t < nb) bsum[t] = sd[t] - v;
}
__global__ void scan3_k(int* __restrict__ rowptr, int* __restrict__ cursor,
                        const int* __restrict__ bsum, int N, int E) {
  int i = blockIdx.x * 256 + threadIdx.x;
  if (i < N) {
    int v = rowptr[i] + bsum[i >> 10];
    rowptr[i] = v;
    cursor[i] = v;
  } else if (i == N) {
    rowptr[N] = E;
  }
}
__global__ void fill_k(const int* __restrict__ src, const int* __restrict__ dst,
                       int* __restrict__ cursor, int* __restrict__ nbr, int E) {
  int i = blockIdx.x * 256 + threadIdx.x;
  if (i < E) {
    int p = atomicAdd(&cursor[dst[i]], 1);
    nbr[p] = src[i];
  }
}

// ---------- dense GEMM (single 128-col output): O = A @ Wl ----------
// Round-4 structure (best measured): linear-coalesced staging into LDS, swapped
// MFMA operands (A-op = weights, B-op = nodes), vector 8-B coalesced stores.
// SRCF32: A = x fp32 stride 130 (bf16-convert while staging, K padded 130->160).
// else:   A = bf16 stride 128.
template<int KC, bool SRCF32>
__global__ __launch_bounds__(256) void gemmL_k(const void* __restrict__ Asrc,
                                               const unsigned short* __restrict__ wpk,
                                               unsigned short* __restrict__ O, int N) {
  constexpr int KP = KC * 32;
  constexpr int LDA = KP + 8;
  __shared__ __align__(16) unsigned short a_s[64][LDA];
  const int tid = threadIdx.x;
  const int node0 = blockIdx.x * 64;

  if constexpr (SRCF32) {
    {  // zero pad cols [130,136) and [136,168): disjoint from data cols [0,130)
      const int zr = tid >> 2, zq = tid & 3;
      v8s z = {0, 0, 0, 0, 0, 0, 0, 0};
      *(v8s*)&a_s[zr][136 + zq * 8] = z;
      if (tid < 192) {
        const int r3 = tid / 3, p3 = tid - 3 * r3;
        *(unsigned int*)&a_s[r3][130 + 2 * p3] = 0u;
      }
    }
    const float* xb = (const float*)Asrc + (long)node0 * 130;
    if (node0 + 64 <= N) {      // full tile: unguarded linear float4 sweep
      float4 v[9];
#pragma unroll
      for (int i = 0; i < 9; ++i) {
        const int g = i * 256 + tid;
        if (g < 2080) v[i] = *(const float4*)(xb + 4 * g);
      }
#pragma unroll
      for (int i = 0; i < 9; ++i) {
        const int g = i * 256 + tid;
        if (g < 2080) {
          const int p0 = 2 * g, p1 = 2 * g + 1;
          const int r0_ = (p0 * 4033) >> 18, r1_ = (p1 * 4033) >> 18;
          const int c0_ = p0 - 65 * r0_, c1_ = p1 - 65 * r1_;
          *(ushort2*)&a_s[r0_][2 * c0_] = pk(make_float2(v[i].x, v[i].y));
          *(ushort2*)&a_s[r1_][2 * c1_] = pk(make_float2(v[i].z, v[i].w));
        }
      }
    } else {                    // partial tail tile: per-pair guarded float2
      for (int i = 0; i < 9; ++i) {
        const int g = i * 256 + tid;
        if (g < 2080) {
#pragma unroll
          for (int h = 0; h < 2; ++h) {
            const int p = 2 * g + h;
            const int r = (p * 4033) >> 18;
            const int c = p - 65 * r;
            float2 vv = make_float2(0.f, 0.f);
            if (node0 + r < N)
              vv = *(const float2*)((const float*)Asrc + (long)(node0 + r) * 130 + 2 * c);
            *(ushort2*)&a_s[r][2 * c] = pk(vv);
          }
        }
      }
    }
  } else {
    const unsigned short* hb = (const unsigned short*)Asrc + (long)node0 * 128;
    v8s v[KC];
#pragma unroll
    for (int i = 0; i < KC; ++i) {
      const int u = i * 256 + tid;
      const int r = u >> 4;
      v[i] = (v8s){0, 0, 0, 0, 0, 0, 0, 0};
      if (node0 + r < N) v[i] = *(const v8s*)(hb + 8 * u);
    }
#pragma unroll
    for (int i = 0; i < KC; ++i) {
      const int u = i * 256 + tid;
      *(v8s*)&a_s[u >> 4][(u & 15) * 8] = v[i];
    }
  }
  __syncthreads();

  const int wave = tid >> 6, lane = tid & 63;
  const int quad = lane >> 4, l16 = lane & 15;
  v4f acc[4][2];
#pragma unroll
  for (int mt = 0; mt < 4; ++mt)
#pragma unroll
    for (int nt = 0; nt < 2; ++nt) acc[mt][nt] = (v4f){0.f, 0.f, 0.f, 0.f};

  // weight fragment (A-operand): row = l16 -> feature (wave*32 + nt*16 + l16)
  const unsigned short* wb = wpk + (wave * 32 + l16) * 32 + quad * 8;
#pragma unroll
  for (int kc = 0; kc < KC; ++kc) {
    v8s wf[2];
#pragma unroll
    for (int nt = 0; nt < 2; ++nt)
      wf[nt] = *(const v8s*)(wb + kc * 4096 + nt * 512);
#pragma unroll
    for (int mt = 0; mt < 4; ++mt) {
      v8s nf = *(const v8s*)(&a_s[mt * 16 + l16][kc * 32 + quad * 8]);
#pragma unroll
      for (int nt = 0; nt < 2; ++nt)
        acc[mt][nt] = __builtin_amdgcn_mfma_f32_16x16x32_bf16(wf[nt], nf, acc[mt][nt], 0, 0, 0);
    }
  }

  // D layout: col=l16 -> node mt*16+l16, row=quad*4+r -> feature. 8-B vector stores.
#pragma unroll
  for (int mt = 0; mt < 4; ++mt) {
    const int rw = node0 + mt * 16 + l16;
    if (rw < N) {
#pragma unroll
      for (int nt = 0; nt < 2; ++nt) {
        const int oc = wave * 32 + nt * 16 + quad * 4;
        v4us v;
        v[0] = f2bf(acc[mt][nt][0]);
        v[1] = f2bf(acc[mt][nt][1]);
        v[2] = f2bf(acc[mt][nt][2]);
        v[3] = f2bf(acc[mt][nt][3]);
        *(v4us*)(O + (long)rw * 128 + oc) = v;
      }
    }
  }
}

// ---------- fused aggregate + ROOT GEMM:
//   out = relu((mean(gsrc[nbr]) + rsrc_tile @ Wr) * s + t)
// 16 nodes/block. Root term computed in-kernel: stage the block's 16 contiguous
// rsrc rows into LDS (bf16), 4 waves x (2 nt x KC) MFMAs -> root LDS (fp32),
// combined with the gathered mean in the epilogue. Eliminates the P_r buffer
// (51 MB write + 51 MB read per layer).
// NO early return: kernel has barriers; OOB nodes are guarded per-op.
template<int KC, bool SRCF32, bool OUTF32>
__global__ __launch_bounds__(256) void spmmR_k(const unsigned short* __restrict__ gsrc,
                                               const void* __restrict__ rsrc,
                                               const unsigned short* __restrict__ wpkr,
                                               const int* __restrict__ rowptr,
                                               const int* __restrict__ nbr,
                                               const float* __restrict__ sc,
                                               const float* __restrict__ tc,
                                               void* __restrict__ out, int N) {
  constexpr int LXS = SRCF32 ? 168 : 136;   // padded strides: 2-way (free) LDS banking
  __shared__ __align__(16) unsigned short xls[16][LXS];
  __shared__ __align__(16) float rls[16][132];
  const int tid = threadIdx.x;
  const int w = tid >> 6, lane = tid & 63;
  const int quad = lane >> 4, l16 = lane & 15;
  const int nb0 = blockIdx.x * 16;

  // ---- stage the block's 16 rsrc rows into xls (bf16) ----
  if constexpr (SRCF32) {
    {  // zero pad cols [130,136) and [136,168)
      if (tid < 64) {
        v8s z = {0, 0, 0, 0, 0, 0, 0, 0};
        *(v8s*)&xls[tid >> 2][136 + (tid & 3) * 8] = z;
      }
      if (tid < 48) {
        const int r3 = tid / 3, p3 = tid - 3 * r3;
        *(unsigned int*)&xls[r3][130 + 2 * p3] = 0u;
      }
    }
    const float* xb = (const float*)rsrc + (long)nb0 * 130;
    if (nb0 + 16 <= N) {   // full tile: linear float4 sweep (520 float4s)
      float4 v[3];
#pragma unroll
      for (int i = 0; i < 3; ++i) {
        const int g = i * 256 + tid;
        if (g < 520) v[i] = *(const float4*)(xb + 4 * g);
      }
#pragma unroll
      for (int i = 0; i < 3; ++i) {
        const int g = i * 256 + tid;
        if (g < 520) {
          const int p0 = 2 * g, p1 = 2 * g + 1;
          const int r0_ = (p0 * 4033) >> 18, r1_ = (p1 * 4033) >> 18;
          const int c0_ = p0 - 65 * r0_, c1_ = p1 - 65 * r1_;
          *(ushort2*)&xls[r0_][2 * c0_] = pk(make_float2(v[i].x, v[i].y));
          *(ushort2*)&xls[r1_][2 * c1_] = pk(make_float2(v[i].z, v[i].w));
        }
      }
    } else {               // tail: per-pair guarded
      for (int i = 0; i < 3; ++i) {
        const int g = i * 256 + tid;
        if (g < 520) {
#pragma unroll
          for (int h = 0; h < 2; ++h) {
            const int p = 2 * g + h;
            const int r = (p * 4033) >> 18;
            const int c = p - 65 * r;
            float2 vv = make_float2(0.f, 0.f);
            if (nb0 + r < N)
              vv = *(const float2*)((const float*)rsrc + (long)(nb0 + r) * 130 + 2 * c);
            *(ushort2*)&xls[r][2 * c] = pk(vv);
          }
        }
      }
    }
  } else {
    // bf16 rows, 128 cols: 256 v8s units, one per thread
    const unsigned short* hb = (const unsigned short*)rsrc + (long)nb0 * 128;
    const int r = tid >> 4, c = (tid & 15) * 8;
    v8s v = {0, 0, 0, 0, 0, 0, 0, 0};
    if (nb0 + r < N) v = *(const v8s*)(hb + (long)r * 128 + c);
    *(v8s*)&xls[r][c] = v;
  }

  // ---- gather setup (independent global loads; interleave with staging) ----
  const int nb = nb0 + w * 4;
  int rp = 0;
  if (lane <= 4 && nb + lane <= N) rp = rowptr[nb + lane];
  int d[4], r0[4], myn[4];
  float2 a[4];
#pragma unroll
  for (int r = 0; r < 4; ++r) {
    r0[r] = __shfl(rp, r, 64);
    const int r1 = __shfl(rp, r + 1, 64);
    d[r] = (nb + r < N) ? (r1 - r0[r]) : 0;
    a[r] = make_float2(0.f, 0.f);
    myn[r] = N;
    if (lane < min(d[r], 64)) myn[r] = nbr[r0[r] + lane];
  }
  const int dm = max(max(d[0], d[1]), max(d[2], d[3]));

  __syncthreads();   // xls ready

  // ---- root GEMM: 16 nodes x 128 feats; wave w covers feats [w*32, w*32+32) ----
  {
    v4f racc[2];
    racc[0] = (v4f){0.f, 0.f, 0.f, 0.f};
    racc[1] = (v4f){0.f, 0.f, 0.f, 0.f};
    const unsigned short* wb = wpkr + (w * 32 + l16) * 32 + quad * 8;
#pragma unroll
    for (int kc = 0; kc < KC; ++kc) {
      v8s nf = *(const v8s*)&xls[l16][kc * 32 + quad * 8];
#pragma unroll
      for (int nt = 0; nt < 2; ++nt) {
        v8s wf = *(const v8s*)(wb + kc * 4096 + nt * 512);
        racc[nt] = __builtin_amdgcn_mfma_f32_16x16x32_bf16(wf, nf, racc[nt], 0, 0, 0);
      }
    }
    // D: col=l16 -> node, row=quad*4+r -> feat offset; store fp32 to root LDS
#pragma unroll
    for (int nt = 0; nt < 2; ++nt)
      *(v4f*)&rls[l16][w * 32 + nt * 16 + quad * 4] = racc[nt];
  }

  // ---- gather-mean over 256-B rows (lane reads one u32 = 2 bf16) ----
  if (dm <= 64) {
    for (int e0 = 0; e0 < dm; e0 += 8) {
      unsigned int u[4][8];
#pragma unroll
      for (int j = 0; j < 8; ++j)
#pragma unroll
        for (int r = 0; r < 4; ++r) {
          const int e = e0 + j;
          const int idx = (e < d[r]) ? __shfl(myn[r], e, 64) : N;
          u[r][j] = *(const unsigned int*)(gsrc + (long)idx * 128 + 2 * lane);
        }
#pragma unroll
      for (int r = 0; r < 4; ++r)
#pragma unroll
        for (int j = 0; j < 8; ++j) {
          a[r].x += bf2f(u[r][j] & 0xffffu);
          a[r].y += bf2f(u[r][j] >> 16);
        }
    }
  } else {  // rare huge-degree fallback
    for (int r = 0; r < 4; ++r) {
      for (int base = r0[r]; base < r0[r] + d[r]; base += 64) {
        const int cnt = min(64, r0[r] + d[r] - base);
        const int mn = (lane < cnt) ? nbr[base + lane] : N;
        for (int e = 0; e < cnt; ++e) {
          const unsigned int uu =
              *(const unsigned int*)(gsrc + (long)__shfl(mn, e, 64) * 128 + 2 * lane);
          a[r].x += bf2f(uu & 0xffffu);
          a[r].y += bf2f(uu >> 16);
        }
      }
    }
  }

  __syncthreads();   // rls ready

  const float2 sv = *(const float2*)(sc + 2 * lane);
  const float2 tv = *(const float2*)(tc + 2 * lane);
#pragma unroll
  for (int r = 0; r < 4; ++r) {
    if (nb + r < N) {
      const float inv = 1.0f / fmaxf((float)d[r], 1.0f);
      const float2 rt = *(const float2*)&rls[w * 4 + r][2 * lane];
      float yx = a[r].x * inv + rt.x;
      float yy = a[r].y * inv + rt.y;
      yx = fmaxf(yx * sv.x + tv.x, 0.f);
      yy = fmaxf(yy * sv.y + tv.y, 0.f);
      if (OUTF32) {
        *(float2*)((float*)out + (long)(nb + r) * 128 + 2 * lane) = make_float2(yx, yy);
      } else {
        *(ushort2*)((unsigned short*)out + (long)(nb + r) * 128 + 2 * lane) =
            pk(make_float2(yx, yy));
      }
    }
  }
}

extern "C" void kernel_launch(void* const* d_in, const int* in_sizes, int n_in,
                              void* d_out, int out_size, void* d_ws, size_t ws_size,
                              hipStream_t stream) {
  const float* x   = (const float*)d_in[0];
  const int*   ei  = (const int*)d_in[1];
  const float* W1l = (const float*)d_in[2];
  const float* b1  = (const float*)d_in[3];
  const float* W1r = (const float*)d_in[4];
  const float* g1  = (const float*)d_in[5];
  const float* be1 = (const float*)d_in[6];
  const float* rm1 = (const float*)d_in[7];
  const float* rv1 = (const float*)d_in[8];
  const float* W2l = (const float*)d_in[9];
  const float* b2  = (const float*)d_in[10];
  const float* W2r = (const float*)d_in[11];
  const float* g2  = (const float*)d_in[12];
  const float* be2 = (const float*)d_in[13];
  const float* rm2 = (const float*)d_in[14];
  const float* rv2 = (const float*)d_in[15];

  const int E = in_sizes[1] / 2;
  const int N = in_sizes[0] / 130;
  const int* src = ei;
  const int* dst = ei + E;

  // workspace carve (~102 MB)
  unsigned short* bufA = (unsigned short*)d_ws;            // P1l -> P2l (gather targets)
  unsigned short* bufB = bufA + (size_t)(N + 1) * 128;     // h1
  unsigned short* wp1l = bufB + (size_t)(N + 1) * 128;     // 5*4096
  unsigned short* wp1r = wp1l + 5 * 4096;                  // 5*4096
  unsigned short* wp2l = wp1r + 5 * 4096;                  // 4*4096
  unsigned short* wp2r = wp2l + 4 * 4096;                  // 4*4096
  float* s1 = (float*)(wp2r + 4 * 4096);
  float* t1 = s1 + 128;
  float* s2 = t1 + 128;
  float* t2 = s2 + 128;
  int* degi   = (int*)(t2 + 128);   // N (reused as cursor)
  int* rowptr = degi + N;           // N+1
  int* bsum   = rowptr + N + 1;     // 256
  int* nbr    = bsum + 256;         // E

  hipLaunchKernelGGL(bn_fold_k, dim3(1), dim3(128), 0, stream,
                     g1, be1, rm1, rv1, b1, g2, be2, rm2, rv2, b2,
                     s1, t1, s2, t2, bufA, N);
  hipLaunchKernelGGL((pack1_k<130, 5>), dim3(80), dim3(256), 0, stream, W1l, wp1l);
  hipLaunchKernelGGL((pack1_k<130, 5>), dim3(80), dim3(256), 0, stream, W1r, wp1r);
  hipLaunchKernelGGL((pack1_k<128, 4>), dim3(64), dim3(256), 0, stream, W2l, wp2l);
  hipLaunchKernelGGL((pack1_k<128, 4>), dim3(64), dim3(256), 0, stream, W2r, wp2r);

  // CSR build
  hipLaunchKernelGGL(zero_i_k, dim3((N + 255) / 256), dim3(256), 0, stream, degi, N);
  hipLaunchKernelGGL(count_k, dim3((E + 255) / 256), dim3(256), 0, stream, dst, degi, E);
  const int nb = (N + 1023) / 1024;
  hipLaunchKernelGGL(scan1_k, dim3(nb), dim3(256), 0, stream, degi, rowptr, bsum, N);
  hipLaunchKernelGGL(scan2_k, dim3(1), dim3(256), 0, stream, bsum, nb);
  hipLaunchKernelGGL(scan3_k, dim3((N + 256) / 256), dim3(256), 0, stream,
                     rowptr, degi, bsum, N, E);
  hipLaunchKernelGGL(fill_k, dim3((E + 255) / 256), dim3(256), 0, stream,
                     src, dst, degi, nbr, E);

  const int ngb = (N + 63) / 64;
  const int nsb = (N + 15) / 16;

  // layer 1: P1l = x @ W1l; h1 = relu((mean(P1l[nbr]) + x_tile@W1r)*s1 + t1')
  hipLaunchKernelGGL((gemmL_k<5, true>), dim3(ngb), dim3(256), 0, stream,
                     (const void*)x, wp1l, bufA, N);
  hipLaunchKernelGGL((spmmR_k<5, true, false>), dim3(nsb), dim3(256), 0, stream,
                     bufA, (const void*)x, wp1r, rowptr, nbr, s1, t1, (void*)bufB, N);
  // layer 2: P2l = h1 @ W2l; out = relu((mean(P2l[nbr]) + h1_tile@W2r)*s2 + t2')
  hipLaunchKernelGGL((gemmL_k<4, false>), dim3(ngb), dim3(256), 0, stream,
                     (const void*)bufB, wp2l, bufA, N);
  hipLaunchKernelGGL((spmmR_k<4, false, true>), dim3(nsb), dim3(256), 0, stream,
                     bufA, (const void*)bufB, wp2r, rowptr, nbr, s2, t2, d_out, N);
}

// Round 7
// 435.893 us; speedup vs baseline: 1.1328x; 1.0572x over previous
//
#include <hip/hip_runtime.h>

typedef short v8s __attribute__((ext_vector_type(8)));
typedef float v4f __attribute__((ext_vector_type(4)));
typedef unsigned short v4us __attribute__((ext_vector_type(4)));

__device__ __forceinline__ unsigned short f2bf(float x) {
  union { float f; unsigned int u; } c; c.f = x;
  unsigned int u = c.u;
  return (unsigned short)((u + 0x7fffu + ((u >> 16) & 1u)) >> 16);
}
__device__ __forceinline__ float bf2f(unsigned int hi16) {
  union { unsigned int u; float f; } c; c.u = hi16 << 16;
  return c.f;
}
__device__ __forceinline__ ushort2 pk(float2 v) {
  ushort2 p; p.x = f2bf(v.x); p.y = f2bf(v.y); return p;
}

// Fold BN scale/shift AND the lin_l bias:  out = relu(z*s + t'), t' = (b - rm)*s + be.
// Also zeroes the gather sentinel row N of bufA (rows < N only are ever written later).
__global__ void bn_fold_k(const float* __restrict__ g1, const float* __restrict__ be1,
                          const float* __restrict__ rm1, const float* __restrict__ rv1,
                          const float* __restrict__ b1,
                          const float* __restrict__ g2, const float* __restrict__ be2,
                          const float* __restrict__ rm2, const float* __restrict__ rv2,
                          const float* __restrict__ b2,
                          float* __restrict__ s1, float* __restrict__ t1,
                          float* __restrict__ s2, float* __restrict__ t2,
                          unsigned short* __restrict__ bufA, int N) {
  int i = threadIdx.x;
  if (i < 128) {
    float sv = g1[i] * rsqrtf(rv1[i] + 1e-5f);
    s1[i] = sv; t1[i] = (b1[i] - rm1[i]) * sv + be1[i];
    float sw = g2[i] * rsqrtf(rv2[i] + 1e-5f);
    s2[i] = sw; t2[i] = (b2[i] - rm2[i]) * sw + be2[i];
  }
  if (i < 64) ((unsigned int*)(bufA + (long)N * 128))[i] = 0u;
}

// Pack one 128-col weight into MFMA A-operand fragments:
// wpk[kc*4096 + n*32 + kk], n in [0,128). k >= K rows are ZERO (K-pad relies on this).
template<int K, int KC>
__global__ void pack1_k(const float* __restrict__ W, unsigned short* __restrict__ wpk) {
  int i = blockIdx.x * 256 + threadIdx.x;
  if (i >= KC * 4096) return;
  int kk = i & 31, n = (i >> 5) & 127, kc = i >> 12;
  int k = kc * 32 + kk;
  wpk[i] = (k < K) ? f2bf(W[k * 128 + n]) : (unsigned short)0;
}

// ---------- CSR build ----------
__global__ void zero_i_k(int* __restrict__ p, int n) {
  int i = blockIdx.x * 256 + threadIdx.x;
  if (i < n) p[i] = 0;
}
__global__ void count_k(const int* __restrict__ dst, int* __restrict__ degi, int E) {
  int i = blockIdx.x * 256 + threadIdx.x;
  if (i < E) atomicAdd(&degi[dst[i]], 1);
}
__global__ __launch_bounds__(256) void scan1_k(const int* __restrict__ degi,
                                               int* __restrict__ rowptr,
                                               int* __restrict__ bsum, int N) {
  __shared__ int sd[256];
  const int t = threadIdx.x;
  const int base = blockIdx.x * 1024 + t * 4;
  int v[4];
#pragma unroll
  for (int j = 0; j < 4; ++j) v[j] = (base + j < N) ? degi[base + j] : 0;
  const int tot = v[0] + v[1] + v[2] + v[3];
  sd[t] = tot;
  __syncthreads();
  for (int off = 1; off < 256; off <<= 1) {
    int o = (t >= off) ? sd[t - off] : 0;
    __syncthreads();
    sd[t] += o;
    __syncthreads();
  }
  int e = sd[t] - tot;
#pragma unroll
  for (int j = 0; j < 4; ++j) {
    if (base + j < N) rowptr[base + j] = e;
    e += v[j];
  }
  if (t == 255) bsum[blockIdx.x] = sd[255];
}
__global__ __launch_bounds__(256) void scan2_k(int* __restrict__ bsum, int nb) {
  __shared__ int sd[256];
  const int t = threadIdx.x;
  const int v = (t < nb) ? bsum[t] : 0;
  sd[t] = v;
  __syncthreads();
  for (int off = 1; off < 256; off <<= 1) {
    int o = (t >= off) ? sd[t - off] : 0;
    __syncthreads();
    sd[t] += o;
    __syncthreads();
  }
  if (t < nb) bsum[t] = sd[t] - v;
}
__global__ void scan3_k(int* __restrict__ rowptr, int* __restrict__ cursor,
                        const int* __restrict__ bsum, int N, int E) {
  int i = blockIdx.x * 256 + threadIdx.x;
  if (i < N) {
    int v = rowptr[i] + bsum[i >> 10];
    rowptr[i] = v;
    cursor[i] = v;
  } else if (i == N) {
    rowptr[N] = E;
  }
}
__global__ void fill_k(const int* __restrict__ src, const int* __restrict__ dst,
                       int* __restrict__ cursor, int* __restrict__ nbr, int E) {
  int i = blockIdx.x * 256 + threadIdx.x;
  if (i < E) {
    int p = atomicAdd(&cursor[dst[i]], 1);
    nbr[p] = src[i];
  }
}

// ---------- dense GEMM (single 128-col output): O = A @ Wl ----------
// Linear-coalesced staging into LDS, swapped MFMA operands (A-op = weights,
// B-op = nodes), vector 8-B coalesced stores.
// SRCF32: A = x fp32 stride 130 (bf16-convert while staging, K padded 130->160).
// else:   A = bf16 stride 128.
template<int KC, bool SRCF32>
__global__ __launch_bounds__(256) void gemmL_k(const void* __restrict__ Asrc,
                                               const unsigned short* __restrict__ wpk,
                                               unsigned short* __restrict__ O, int N) {
  constexpr int KP = KC * 32;
  constexpr int LDA = KP + 8;
  __shared__ __align__(16) unsigned short a_s[64][LDA];
  const int tid = threadIdx.x;
  const int node0 = blockIdx.x * 64;

  if constexpr (SRCF32) {
    {  // zero pad cols [130,136) and [136,168): disjoint from data cols [0,130)
      const int zr = tid >> 2, zq = tid & 3;
      v8s z = {0, 0, 0, 0, 0, 0, 0, 0};
      *(v8s*)&a_s[zr][136 + zq * 8] = z;
      if (tid < 192) {
        const int r3 = tid / 3, p3 = tid - 3 * r3;
        *(unsigned int*)&a_s[r3][130 + 2 * p3] = 0u;
      }
    }
    const float* xb = (const float*)Asrc + (long)node0 * 130;
    if (node0 + 64 <= N) {      // full tile: unguarded linear float4 sweep
      float4 v[9];
#pragma unroll
      for (int i = 0; i < 9; ++i) {
        const int g = i * 256 + tid;
        if (g < 2080) v[i] = *(const float4*)(xb + 4 * g);
      }
#pragma unroll
      for (int i = 0; i < 9; ++i) {
        const int g = i * 256 + tid;
        if (g < 2080) {
          const int p0 = 2 * g, p1 = 2 * g + 1;
          const int r0_ = (p0 * 4033) >> 18, r1_ = (p1 * 4033) >> 18;
          const int c0_ = p0 - 65 * r0_, c1_ = p1 - 65 * r1_;
          *(ushort2*)&a_s[r0_][2 * c0_] = pk(make_float2(v[i].x, v[i].y));
          *(ushort2*)&a_s[r1_][2 * c1_] = pk(make_float2(v[i].z, v[i].w));
        }
      }
    } else {                    // partial tail tile: per-pair guarded float2
      for (int i = 0; i < 9; ++i) {
        const int g = i * 256 + tid;
        if (g < 2080) {
#pragma unroll
          for (int h = 0; h < 2; ++h) {
            const int p = 2 * g + h;
            const int r = (p * 4033) >> 18;
            const int c = p - 65 * r;
            float2 vv = make_float2(0.f, 0.f);
            if (node0 + r < N)
              vv = *(const float2*)((const float*)Asrc + (long)(node0 + r) * 130 + 2 * c);
            *(ushort2*)&a_s[r][2 * c] = pk(vv);
          }
        }
      }
    }
  } else {
    const unsigned short* hb = (const unsigned short*)Asrc + (long)node0 * 128;
    v8s v[KC];
#pragma unroll
    for (int i = 0; i < KC; ++i) {
      const int u = i * 256 + tid;
      const int r = u >> 4;
      v[i] = (v8s){0, 0, 0, 0, 0, 0, 0, 0};
      if (node0 + r < N) v[i] = *(const v8s*)(hb + 8 * u);
    }
#pragma unroll
    for (int i = 0; i < KC; ++i) {
      const int u = i * 256 + tid;
      *(v8s*)&a_s[u >> 4][(u & 15) * 8] = v[i];
    }
  }
  __syncthreads();

  const int wave = tid >> 6, lane = tid & 63;
  const int quad = lane >> 4, l16 = lane & 15;
  v4f acc[4][2];
#pragma unroll
  for (int mt = 0; mt < 4; ++mt)
#pragma unroll
    for (int nt = 0; nt < 2; ++nt) acc[mt][nt] = (v4f){0.f, 0.f, 0.f, 0.f};

  // weight fragment (A-operand): row = l16 -> feature (wave*32 + nt*16 + l16)
  const unsigned short* wb = wpk + (wave * 32 + l16) * 32 + quad * 8;
#pragma unroll
  for (int kc = 0; kc < KC; ++kc) {
    v8s wf[2];
#pragma unroll
    for (int nt = 0; nt < 2; ++nt)
      wf[nt] = *(const v8s*)(wb + kc * 4096 + nt * 512);
#pragma unroll
    for (int mt = 0; mt < 4; ++mt) {
      v8s nf = *(const v8s*)(&a_s[mt * 16 + l16][kc * 32 + quad * 8]);
#pragma unroll
      for (int nt = 0; nt < 2; ++nt)
        acc[mt][nt] = __builtin_amdgcn_mfma_f32_16x16x32_bf16(wf[nt], nf, acc[mt][nt], 0, 0, 0);
    }
  }

  // D layout: col=l16 -> node mt*16+l16, row=quad*4+r -> feature. 8-B vector stores.
#pragma unroll
  for (int mt = 0; mt < 4; ++mt) {
    const int rw = node0 + mt * 16 + l16;
    if (rw < N) {
#pragma unroll
      for (int nt = 0; nt < 2; ++nt) {
        const int oc = wave * 32 + nt * 16 + quad * 4;
        v4us v;
        v[0] = f2bf(acc[mt][nt][0]);
        v[1] = f2bf(acc[mt][nt][1]);
        v[2] = f2bf(acc[mt][nt][2]);
        v[3] = f2bf(acc[mt][nt][3]);
        *(v4us*)(O + (long)rw * 128 + oc) = v;
      }
    }
  }
}

// ---------- fused aggregate + ROOT GEMM, SCALARIZED gather control path:
//   out = relu((mean(gsrc[nbr]) + rsrc_tile @ Wr) * s + t)
// 16 nodes/block, 4 nodes/wave. All CSR state (rowptr, degree, neighbor index) is
// wave-uniform: w is readfirstlane'd so the compiler emits s_load/SALU for it.
// Per gathered u32: 1 VALU addr + 4 unpack (was ~9 VALU + 1 ds_bpermute).
// Ragged slots select the zeroed sentinel row N via s_cselect; nbr over-reads are
// clamped to E-1 (value discarded). Uniform chunk loop handles ANY degree (the old
// 64-cap fallback is gone).
template<int KC, bool SRCF32, bool OUTF32>
__global__ __launch_bounds__(256) void spmmR_k(const unsigned short* __restrict__ gsrc,
                                               const void* __restrict__ rsrc,
                                               const unsigned short* __restrict__ wpkr,
                                               const int* __restrict__ rowptr,
                                               const int* __restrict__ nbr,
                                               const float* __restrict__ sc,
                                               const float* __restrict__ tc,
                                               void* __restrict__ out, int N, int E) {
  constexpr int LXS = SRCF32 ? 168 : 136;   // padded strides: 2-way (free) LDS banking
  __shared__ __align__(16) unsigned short xls[16][LXS];
  __shared__ __align__(16) float rls[16][132];
  const int tid = threadIdx.x;
  const int lane = tid & 63;
  const int wu = __builtin_amdgcn_readfirstlane(tid >> 6);   // uniform wave id
  const int quad = lane >> 4, l16 = lane & 15;
  const int nb0 = blockIdx.x * 16;

  // ---- stage the block's 16 rsrc rows into xls (bf16) ----
  if constexpr (SRCF32) {
    {  // zero pad cols [130,136) and [136,168)
      if (tid < 64) {
        v8s z = {0, 0, 0, 0, 0, 0, 0, 0};
        *(v8s*)&xls[tid >> 2][136 + (tid & 3) * 8] = z;
      }
      if (tid < 48) {
        const int r3 = tid / 3, p3 = tid - 3 * r3;
        *(unsigned int*)&xls[r3][130 + 2 * p3] = 0u;
      }
    }
    const float* xb = (const float*)rsrc + (long)nb0 * 130;
    if (nb0 + 16 <= N) {   // full tile: linear float4 sweep (520 float4s)
      float4 v[3];
#pragma unroll
      for (int i = 0; i < 3; ++i) {
        const int g = i * 256 + tid;
        if (g < 520) v[i] = *(const float4*)(xb + 4 * g);
      }
#pragma unroll
      for (int i = 0; i < 3; ++i) {
        const int g = i * 256 + tid;
        if (g < 520) {
          const int p0 = 2 * g, p1 = 2 * g + 1;
          const int r0_ = (p0 * 4033) >> 18, r1_ = (p1 * 4033) >> 18;
          const int c0_ = p0 - 65 * r0_, c1_ = p1 - 65 * r1_;
          *(ushort2*)&xls[r0_][2 * c0_] = pk(make_float2(v[i].x, v[i].y));
          *(ushort2*)&xls[r1_][2 * c1_] = pk(make_float2(v[i].z, v[i].w));
        }
      }
    } else {               // tail: per-pair guarded
      for (int i = 0; i < 3; ++i) {
        const int g = i * 256 + tid;
        if (g < 520) {
#pragma unroll
          for (int h = 0; h < 2; ++h) {
            const int p = 2 * g + h;
            const int r = (p * 4033) >> 18;
            const int c = p - 65 * r;
            float2 vv = make_float2(0.f, 0.f);
            if (nb0 + r < N)
              vv = *(const float2*)((const float*)rsrc + (long)(nb0 + r) * 130 + 2 * c);
            *(ushort2*)&xls[r][2 * c] = pk(vv);
          }
        }
      }
    }
  } else {
    // bf16 rows, 128 cols: 256 v8s units, one per thread
    const unsigned short* hb = (const unsigned short*)rsrc + (long)nb0 * 128;
    const int r = tid >> 4, c = (tid & 15) * 8;
    v8s v = {0, 0, 0, 0, 0, 0, 0, 0};
    if (nb0 + r < N) v = *(const v8s*)(hb + (long)r * 128 + c);
    *(v8s*)&xls[r][c] = v;
  }

  // ---- scalar CSR setup (all wave-uniform -> SALU/s_load) ----
  const int nb = nb0 + wu * 4;
  int r0[4], d[4];
#pragma unroll
  for (int r = 0; r < 4; ++r) {
    const int i0 = min(nb + r, N);
    const int i1 = min(nb + r + 1, N);
    r0[r] = rowptr[i0];
    const int r1 = rowptr[i1];
    d[r] = (nb + r < N) ? (r1 - r0[r]) : 0;
  }
  const int dm = max(max(d[0], d[1]), max(d[2], d[3]));
  float2 a[4];
#pragma unroll
  for (int r = 0; r < 4; ++r) a[r] = make_float2(0.f, 0.f);

  __syncthreads();   // xls ready

  // ---- root GEMM: 16 nodes x 128 feats; wave wu covers feats [wu*32, wu*32+32) ----
  {
    v4f racc[2];
    racc[0] = (v4f){0.f, 0.f, 0.f, 0.f};
    racc[1] = (v4f){0.f, 0.f, 0.f, 0.f};
    const unsigned short* wb = wpkr + (wu * 32 + l16) * 32 + quad * 8;
#pragma unroll
    for (int kc = 0; kc < KC; ++kc) {
      v8s nf = *(const v8s*)&xls[l16][kc * 32 + quad * 8];
#pragma unroll
      for (int nt = 0; nt < 2; ++nt) {
        v8s wf = *(const v8s*)(wb + kc * 4096 + nt * 512);
        racc[nt] = __builtin_amdgcn_mfma_f32_16x16x32_bf16(wf, nf, racc[nt], 0, 0, 0);
      }
    }
#pragma unroll
    for (int nt = 0; nt < 2; ++nt)
      *(v4f*)&rls[l16][wu * 32 + nt * 16 + quad * 4] = racc[nt];
  }

  // ---- gather-mean: uniform chunk loop, scalar addresses, lane covers 2 feats ----
  const int lofs = lane << 1;   // shorts offset within 128-elem row
  for (int e0 = 0; e0 < dm; e0 += 8) {
    unsigned int u[4][8];
#pragma unroll
    for (int j = 0; j < 8; ++j)
#pragma unroll
      for (int r = 0; r < 4; ++r) {
        const int e = e0 + j;
        const int nv = nbr[min(r0[r] + e, E - 1)];        // uniform s_load (clamped)
        const int idx = (e < d[r]) ? nv : N;              // uniform s_cselect
        u[r][j] = *(const unsigned int*)(gsrc + ((long)idx << 7) + lofs);
      }
#pragma unroll
    for (int r = 0; r < 4; ++r)
#pragma unroll
      for (int j = 0; j < 8; ++j) {
        a[r].x += bf2f(u[r][j] & 0xffffu);
        a[r].y += bf2f(u[r][j] >> 16);
      }
  }

  __syncthreads();   // rls ready

  const float2 sv = *(const float2*)(sc + 2 * lane);
  const float2 tv = *(const float2*)(tc + 2 * lane);
#pragma unroll
  for (int r = 0; r < 4; ++r) {
    if (nb + r < N) {
      const float inv = 1.0f / fmaxf((float)d[r], 1.0f);
      const float2 rt = *(const float2*)&rls[wu * 4 + r][2 * lane];
      float yx = a[r].x * inv + rt.x;
      float yy = a[r].y * inv + rt.y;
      yx = fmaxf(yx * sv.x + tv.x, 0.f);
      yy = fmaxf(yy * sv.y + tv.y, 0.f);
      if (OUTF32) {
        *(float2*)((float*)out + (long)(nb + r) * 128 + 2 * lane) = make_float2(yx, yy);
      } else {
        *(ushort2*)((unsigned short*)out + (long)(nb + r) * 128 + 2 * lane) =
            pk(make_float2(yx, yy));
      }
    }
  }
}

extern "C" void kernel_launch(void* const* d_in, const int* in_sizes, int n_in,
                              void* d_out, int out_size, void* d_ws, size_t ws_size,
                              hipStream_t stream) {
  const float* x   = (const float*)d_in[0];
  const int*   ei  = (const int*)d_in[1];
  const float* W1l = (const float*)d_in[2];
  const float* b1  = (const float*)d_in[3];
  const float* W1r = (const float*)d_in[4];
  const float* g1  = (const float*)d_in[5];
  const float* be1 = (const float*)d_in[6];
  const float* rm1 = (const float*)d_in[7];
  const float* rv1 = (const float*)d_in[8];
  const float* W2l = (const float*)d_in[9];
  const float* b2  = (const float*)d_in[10];
  const float* W2r = (const float*)d_in[11];
  const float* g2  = (const float*)d_in[12];
  const float* be2 = (const float*)d_in[13];
  const float* rm2 = (const float*)d_in[14];
  const float* rv2 = (const float*)d_in[15];

  const int E = in_sizes[1] / 2;
  const int N = in_sizes[0] / 130;
  const int* src = ei;
  const int* dst = ei + E;

  // workspace carve (~102 MB)
  unsigned short* bufA = (unsigned short*)d_ws;            // P1l -> P2l (gather targets)
  unsigned short* bufB = bufA + (size_t)(N + 1) * 128;     // h1
  unsigned short* wp1l = bufB + (size_t)(N + 1) * 128;     // 5*4096
  unsigned short* wp1r = wp1l + 5 * 4096;                  // 5*4096
  unsigned short* wp2l = wp1r + 5 * 4096;                  // 4*4096
  unsigned short* wp2r = wp2l + 4 * 4096;                  // 4*4096
  float* s1 = (float*)(wp2r + 4 * 4096);
  float* t1 = s1 + 128;
  float* s2 = t1 + 128;
  float* t2 = s2 + 128;
  int* degi   = (int*)(t2 + 128);   // N (reused as cursor)
  int* rowptr = degi + N;           // N+1
  int* bsum   = rowptr + N + 1;     // 256
  int* nbr    = bsum + 256;         // E (+ slack beyond for clamped over-reads)

  hipLaunchKernelGGL(bn_fold_k, dim3(1), dim3(128), 0, stream,
                     g1, be1, rm1, rv1, b1, g2, be2, rm2, rv2, b2,
                     s1, t1, s2, t2, bufA, N);
  hipLaunchKernelGGL((pack1_k<130, 5>), dim3(80), dim3(256), 0, stream, W1l, wp1l);
  hipLaunchKernelGGL((pack1_k<130, 5>), dim3(80), dim3(256), 0, stream, W1r, wp1r);
  hipLaunchKernelGGL((pack1_k<128, 4>), dim3(64), dim3(256), 0, stream, W2l, wp2l);
  hipLaunchKernelGGL((pack1_k<128, 4>), dim3(64), dim3(256), 0, stream, W2r, wp2r);

  // CSR build
  hipLaunchKernelGGL(zero_i_k, dim3((N + 255) / 256), dim3(256), 0, stream, degi, N);
  hipLaunchKernelGGL(count_k, dim3((E + 255) / 256), dim3(256), 0, stream, dst, degi, E);
  const int nb = (N + 1023) / 1024;
  hipLaunchKernelGGL(scan1_k, dim3(nb), dim3(256), 0, stream, degi, rowptr, bsum, N);
  hipLaunchKernelGGL(scan2_k, dim3(1), dim3(256), 0, stream, bsum, nb);
  hipLaunchKernelGGL(scan3_k, dim3((N + 256) / 256), dim3(256), 0, stream,
                     rowptr, degi, bsum, N, E);
  hipLaunchKernelGGL(fill_k, dim3((E + 255) / 256), dim3(256), 0, stream,
                     src, dst, degi, nbr, E);

  const int ngb = (N + 63) / 64;
  const int nsb = (N + 15) / 16;

  // layer 1: P1l = x @ W1l; h1 = relu((mean(P1l[nbr]) + x_tile@W1r)*s1 + t1')
  hipLaunchKernelGGL((gemmL_k<5, true>), dim3(ngb), dim3(256), 0, stream,
                     (const void*)x, wp1l, bufA, N);
  hipLaunchKernelGGL((spmmR_k<5, true, false>), dim3(nsb), dim3(256), 0, stream,
                     bufA, (const void*)x, wp1r, rowptr, nbr, s1, t1, (void*)bufB, N, E);
  // layer 2: P2l = h1 @ W2l; out = relu((mean(P2l[nbr]) + h1_tile@W2r)*s2 + t2')
  hipLaunchKernelGGL((gemmL_k<4, false>), dim3(ngb), dim3(256), 0, stream,
                     (const void*)bufB, wp2l, bufA, N);
  hipLaunchKernelGGL((spmmR_k<4, false, true>), dim3(nsb), dim3(256), 0, stream,
                     bufA, (const void*)bufB, wp2r, rowptr, nbr, s2, t2, d_out, N, E);
}